// Round 1
// baseline (401.084 us; speedup 1.0000x reference)
//
#include <hip/hip_runtime.h>
#include <cstdint>

// Problem constants (fixed by the reference setup)
#define BB   16      // batch
#define AA   16      // annotations per image
#define KK   80      // classes
#define NLEV 5       // pyramid levels (strides 8..128)
#define PP   21824   // total pyramid positions

// ---------------- workspace layout (bytes) ----------------
//     0: float cls_sum[16]
//    64: float reg_sum[16]
//   128: int   n_eff[16]
//   256: uint  clsmask[B*K]            (5120 B)   -> ends 5376
//  5376: int   bounds[B*A*NLEV*8]     (40960 B)   -> ends 46336
// 46336: float proj[B*A*NLEV*4]       (20480 B)   -> ends 66816
// 66816: uint  masks[B*P]           (1396736 B)   -> ends ~1.46 MB
#define WS_CLSMASK 256
#define WS_BOUNDS  5376
#define WS_PROJ    46336
#define WS_MASKS   66816

// -------------------------------------------------------------------
// Kernel 1: per (b, annotation, level) projected boxes + integer mask
// bounds; per (b, class) 16-bit annotation membership mask.
// -------------------------------------------------------------------
__global__ void prep_kernel(const float* __restrict__ ann,   // B*A*5
                            unsigned int* __restrict__ clsmask,
                            int* __restrict__ bounds,
                            float* __restrict__ proj)
{
#pragma clang fp contract(off)
    int tid = blockIdx.x * blockDim.x + threadIdx.x;
    if (tid < BB * AA * NLEV) {
        int li = tid % NLEV;
        int a  = (tid / NLEV) % AA;
        int b  = tid / (NLEV * AA);
        const float* bx = ann + (b * AA + a) * 5;
        float s = (float)(8 << li);
        float p0 = floorf((bx[0] + s - 1.0f) / s);
        float p1 = floorf((bx[1] + s - 1.0f) / s);
        float p2 = floorf((bx[2] + s - 1.0f) / s);
        float p3 = floorf((bx[3] + s - 1.0f) / s);
        float pw = p2 - p0, ph = p3 - p1;
        // eff shrink f = (1-0.2)/2 = 0.4 ; ign shrink f = (1-0.5)/2 = 0.25
        float e0 = p0 + 0.4f * pw,  e1 = p1 + 0.4f * ph;
        float e2 = p2 - 0.4f * pw,  e3 = p3 - 0.4f * ph;
        float i0 = p0 + 0.25f * pw, i1 = p1 + 0.25f * ph;
        float i2 = p2 - 0.25f * pw, i3 = p3 - 0.25f * ph;
        int* o = bounds + tid * 8;
        o[0] = (int)floorf(e0);          // x >= this
        o[1] = (int)floorf(e2 + 1.0f);   // x <= this
        o[2] = (int)floorf(e1);          // y >= this
        o[3] = (int)floorf(e3 + 1.0f);   // y <= this
        o[4] = (int)floorf(i0 + 1.0f);   // ign x >=
        o[5] = (int)floorf(i2);          // ign x <=
        o[6] = (int)floorf(i1 + 1.0f);   // ign y >=
        o[7] = (int)floorf(i3);          // ign y <=
        float* q = proj + tid * 4;
        q[0] = p0; q[1] = p1; q[2] = p2; q[3] = p3;
    } else if (tid < BB * AA * NLEV + BB * KK) {
        int i = tid - BB * AA * NLEV;
        int k = i % KK;
        int b = i / KK;
        unsigned int m = 0;
        for (int a = 0; a < AA; ++a) {
            int cid = (int)ann[(b * AA + a) * 5 + 4];
            if (cid == k) m |= (1u << a);
        }
        clsmask[b * KK + k] = m;
    }
}

// -------------------------------------------------------------------
// Kernel 2: per (b, position): 16-bit eff/ign coverage masks, regression
// (IoU) loss weighted by # of distinct positive classes, n_eff count.
// -------------------------------------------------------------------
__global__ void __launch_bounds__(256)
mask_kernel(const float* __restrict__ reg,   // B*P*4
            const int* __restrict__ xg, const int* __restrict__ yg,
            const int* __restrict__ lev,
            const float* __restrict__ ann,
            const int* __restrict__ bounds, const float* __restrict__ proj,
            unsigned int* __restrict__ masks,
            float* __restrict__ reg_sum, int* __restrict__ n_eff)
{
    __shared__ int   sb[AA * NLEV * 8];
    __shared__ float sp[AA * NLEV * 4];
    __shared__ int   scid[AA];
    __shared__ float swr[4];
    __shared__ int   swn[4];
    int b = blockIdx.y;
    int t = threadIdx.x;
    for (int j = t; j < AA * NLEV * 8; j += blockDim.x) sb[j] = bounds[b * AA * NLEV * 8 + j];
    for (int j = t; j < AA * NLEV * 4; j += blockDim.x) sp[j] = proj[b * AA * NLEV * 4 + j];
    if (t < AA) scid[t] = (int)ann[(b * AA + t) * 5 + 4];
    __syncthreads();

    int p = blockIdx.x * blockDim.x + t;
    float my_r = 0.0f;
    int   my_n = 0;
    if (p < PP) {
        int x = xg[p], y = yg[p], li = lev[p];
        unsigned int em = 0, im = 0;
        for (int a = 0; a < AA; ++a) {
            const int* o = &sb[(a * NLEV + li) * 8];
            int me = (x >= o[0]) & (x <= o[1]) & (y >= o[2]) & (y <= o[3]);
            int mi = (x >= o[4]) & (x <= o[5]) & (y >= o[6]) & (y <= o[7]);
            em |= (unsigned int)me << a;
            im |= (unsigned int)mi << a;
        }
        masks[b * PP + p] = em | (im << 16);

        // distinct positive classes at this position
        unsigned long long lo = 0; unsigned int hi = 0;
        unsigned int m = em;
        while (m) {
            int a = __ffs(m) - 1; m &= m - 1;
            int c = scid[a];
            if (c < 64) lo |= 1ull << c; else hi |= 1u << (c - 64);
        }
        int npos = __popcll(lo) + __popc(hi);

        // box of LAST covering annotation (default A-1 when none)
        int last = em ? (31 - __clz(em)) : (AA - 1);
        const float* pb = &sp[(last * NLEV + li) * 4];
        float xf = (float)x, yf = (float)y;
        float t0 = (xf - pb[0]) * 0.25f;
        float t1 = (pb[2] - xf) * 0.25f;
        float t2 = (yf - pb[1]) * 0.25f;
        float t3 = (pb[3] - yf) * 0.25f;
        const float4 r4 = ((const float4*)reg)[(size_t)b * PP + p];
        float x_gt = (t2 + t3 + 1.0f) * (t0 + t1 + 1.0f);
        float x_pr = (r4.z + r4.w + 1.0f) * (r4.x + r4.y + 1.0f);
        float ih = fminf(t2, r4.z) + fminf(t3, r4.w) + 1.0f;
        float iw = fminf(t0, r4.x) + fminf(t1, r4.y) + 1.0f;
        float inter = ih * iw;
        float iou = inter / (x_pr + x_gt - inter);
        iou = fminf(fmaxf(iou, 1e-4f), 1.0f - 1e-4f);
        float rl = -logf(iou);
        my_r = rl * (float)npos;
        my_n = npos;
    }

    // wave64 + cross-wave reduce, one atomic pair per block
    for (int off = 32; off > 0; off >>= 1) {
        my_r += __shfl_down(my_r, off);
        my_n += __shfl_down(my_n, off);
    }
    int lane = t & 63, wv = t >> 6;
    if (lane == 0) { swr[wv] = my_r; swn[wv] = my_n; }
    __syncthreads();
    if (t == 0) {
        float rs = 0.0f; int ns = 0;
        for (int w = 0; w < (256 >> 6); ++w) { rs += swr[w]; ns += swn[w]; }
        atomicAdd(&reg_sum[b], rs);
        atomicAdd(&n_eff[b], ns);
    }
}

// -------------------------------------------------------------------
// Kernel 3: streaming focal-loss over (b, p, k). HBM-bound on the
// 111.7 MB classifications tensor; float4 loads, one __logf per elem.
// -------------------------------------------------------------------
__device__ __forceinline__ float focal_term(float c, unsigned int em,
                                            unsigned int im, unsigned int cm)
{
    float cc  = fminf(fmaxf(c, 1e-4f), 1.0f - 1e-4f);
    bool  pos = (em & cm) != 0;
    bool  ign = (!pos) && ((im & cm) != 0);
    float arg = pos ? cc : (1.0f - cc);   // log argument
    float fwt = 1.0f - arg;               // == (pos ? 1-cc : cc)
    float af  = pos ? 0.25f : 0.75f;
    float l   = af * fwt * fwt * (-__logf(arg));
    return ign ? 0.0f : l;
}

__global__ void __launch_bounds__(256)
cls_kernel(const float4* __restrict__ cls4,       // B * (P*K/4)
           const unsigned int* __restrict__ masks,
           const unsigned int* __restrict__ clsmask_g,
           float* __restrict__ cls_sum)
{
    __shared__ uint4 scm[KK / 4];   // 20 x uint4 = per-class annotation masks
    __shared__ float sws[4];
    int b = blockIdx.y;
    int t = threadIdx.x;
    if (t < KK / 4) scm[t] = ((const uint4*)clsmask_g)[b * (KK / 4) + t];
    __syncthreads();

    const int V = PP * KK / 4;   // 436480 float4 per image
    const float4* base = cls4 + (size_t)b * V;
    const unsigned int* mb = masks + b * PP;
    float acc = 0.0f;
    for (int i = blockIdx.x * blockDim.x + t; i < V; i += gridDim.x * blockDim.x) {
        int p  = i / (KK / 4);
        int k4 = i - p * (KK / 4);
        float4 c = base[i];
        unsigned int mk = mb[p];
        unsigned int em = mk & 0xFFFFu, im = mk >> 16;
        uint4 cm = scm[k4];
        acc += focal_term(c.x, em, im, cm.x);
        acc += focal_term(c.y, em, im, cm.y);
        acc += focal_term(c.z, em, im, cm.z);
        acc += focal_term(c.w, em, im, cm.w);
    }
    for (int off = 32; off > 0; off >>= 1) acc += __shfl_down(acc, off);
    int lane = t & 63, wv = t >> 6;
    if (lane == 0) sws[wv] = acc;
    __syncthreads();
    if (t == 0) {
        float s = sws[0] + sws[1] + sws[2] + sws[3];
        atomicAdd(&cls_sum[b], s);
    }
}

// -------------------------------------------------------------------
// Kernel 4: finalize means
// -------------------------------------------------------------------
__global__ void final_kernel(const float* __restrict__ cls_sum,
                             const float* __restrict__ reg_sum,
                             const int* __restrict__ n_eff,
                             float* __restrict__ out)
{
    int t = threadIdx.x;  // 64 threads, lanes 0..15 active
    float c = 0.0f, r = 0.0f;
    if (t < BB) {
        int n = n_eff[t];
        float d = fmaxf((float)n, 1.0f);
        c = cls_sum[t] / d;
        r = (n > 0) ? (reg_sum[t] / d) : 0.0f;
    }
    for (int off = 32; off > 0; off >>= 1) {
        c += __shfl_down(c, off);
        r += __shfl_down(r, off);
    }
    if (t == 0) {
        out[0] = c * (1.0f / BB);
        out[1] = r * (1.0f / BB);
    }
}

extern "C" void kernel_launch(void* const* d_in, const int* in_sizes, int n_in,
                              void* d_out, int out_size, void* d_ws, size_t ws_size,
                              hipStream_t stream)
{
    const float* cls = (const float*)d_in[0];
    const float* reg = (const float*)d_in[1];
    const float* ann = (const float*)d_in[2];
    // d_in[3] = image (unused)
    const int* xg = (const int*)d_in[4];
    const int* yg = (const int*)d_in[5];
    const int* lv = (const int*)d_in[6];
    float* out = (float*)d_out;

    char* ws = (char*)d_ws;
    float* cls_sum = (float*)(ws + 0);
    float* reg_sum = (float*)(ws + 64);
    int*   n_eff   = (int*)(ws + 128);
    unsigned int* clsmask = (unsigned int*)(ws + WS_CLSMASK);
    int*   bounds  = (int*)(ws + WS_BOUNDS);
    float* proj    = (float*)(ws + WS_PROJ);
    unsigned int* masks = (unsigned int*)(ws + WS_MASKS);

    // zero the accumulators (ws is poisoned 0xAA before every launch)
    hipMemsetAsync(ws, 0, 192, stream);

    prep_kernel<<<10, 256, 0, stream>>>(ann, clsmask, bounds, proj);

    dim3 g2((PP + 255) / 256, BB);
    mask_kernel<<<g2, 256, 0, stream>>>(reg, xg, yg, lv, ann, bounds, proj,
                                        masks, reg_sum, n_eff);

    dim3 g3(512, BB);
    cls_kernel<<<g3, 256, 0, stream>>>((const float4*)cls, masks, clsmask, cls_sum);

    final_kernel<<<1, 64, 0, stream>>>(cls_sum, reg_sum, n_eff, out);
}

// Round 2
// 348.666 us; speedup vs baseline: 1.1503x; 1.1503x over previous
//
#include <hip/hip_runtime.h>
#include <cstdint>

// Problem constants (fixed by the reference setup)
#define BB   16      // batch
#define AA   16      // annotations per image
#define KK   80      // classes
#define NLEV 5       // pyramid levels (strides 8..128)
#define PP   21824   // total pyramid positions

// ---------------- workspace layout (bytes) ----------------
#define WS_CLSMASK 256
#define WS_BOUNDS  5376
#define WS_PROJ    46336
#define WS_MASKS   66816

// -------------------------------------------------------------------
// Kernel 1: per (b, annotation, level) projected boxes + integer mask
// bounds; per (b, class) 16-bit annotation membership mask.
// -------------------------------------------------------------------
__global__ void prep_kernel(const float* __restrict__ ann,   // B*A*5
                            unsigned int* __restrict__ clsmask,
                            int* __restrict__ bounds,
                            float* __restrict__ proj)
{
#pragma clang fp contract(off)
    int tid = blockIdx.x * blockDim.x + threadIdx.x;
    if (tid < BB * AA * NLEV) {
        int li = tid % NLEV;
        int a  = (tid / NLEV) % AA;
        int b  = tid / (NLEV * AA);
        const float* bx = ann + (b * AA + a) * 5;
        float s = (float)(8 << li);
        float p0 = floorf((bx[0] + s - 1.0f) / s);
        float p1 = floorf((bx[1] + s - 1.0f) / s);
        float p2 = floorf((bx[2] + s - 1.0f) / s);
        float p3 = floorf((bx[3] + s - 1.0f) / s);
        float pw = p2 - p0, ph = p3 - p1;
        // eff shrink f = (1-0.2)/2 = 0.4 ; ign shrink f = (1-0.5)/2 = 0.25
        float e0 = p0 + 0.4f * pw,  e1 = p1 + 0.4f * ph;
        float e2 = p2 - 0.4f * pw,  e3 = p3 - 0.4f * ph;
        float i0 = p0 + 0.25f * pw, i1 = p1 + 0.25f * ph;
        float i2 = p2 - 0.25f * pw, i3 = p3 - 0.25f * ph;
        int* o = bounds + tid * 8;
        o[0] = (int)floorf(e0);          // x >= this
        o[1] = (int)floorf(e2 + 1.0f);   // x <= this
        o[2] = (int)floorf(e1);          // y >= this
        o[3] = (int)floorf(e3 + 1.0f);   // y <= this
        o[4] = (int)floorf(i0 + 1.0f);   // ign x >=
        o[5] = (int)floorf(i2);          // ign x <=
        o[6] = (int)floorf(i1 + 1.0f);   // ign y >=
        o[7] = (int)floorf(i3);          // ign y <=
        float* q = proj + tid * 4;
        q[0] = p0; q[1] = p1; q[2] = p2; q[3] = p3;
    } else if (tid < BB * AA * NLEV + BB * KK) {
        int i = tid - BB * AA * NLEV;
        int k = i % KK;
        int b = i / KK;
        unsigned int m = 0;
        for (int a = 0; a < AA; ++a) {
            int cid = (int)ann[(b * AA + a) * 5 + 4];
            if (cid == k) m |= (1u << a);
        }
        clsmask[b * KK + k] = m;
    }
}

// -------------------------------------------------------------------
// Kernel 2: per (b, position): 16-bit eff/ign coverage masks, regression
// (IoU) loss weighted by # of distinct positive classes, n_eff count.
// -------------------------------------------------------------------
__global__ void __launch_bounds__(256)
mask_kernel(const float* __restrict__ reg,   // B*P*4
            const int* __restrict__ xg, const int* __restrict__ yg,
            const int* __restrict__ lev,
            const float* __restrict__ ann,
            const int* __restrict__ bounds, const float* __restrict__ proj,
            unsigned int* __restrict__ masks,
            float* __restrict__ reg_sum, int* __restrict__ n_eff)
{
    __shared__ int   sb[AA * NLEV * 8];
    __shared__ float sp[AA * NLEV * 4];
    __shared__ int   scid[AA];
    __shared__ float swr[4];
    __shared__ int   swn[4];
    int b = blockIdx.y;
    int t = threadIdx.x;
    for (int j = t; j < AA * NLEV * 8; j += blockDim.x) sb[j] = bounds[b * AA * NLEV * 8 + j];
    for (int j = t; j < AA * NLEV * 4; j += blockDim.x) sp[j] = proj[b * AA * NLEV * 4 + j];
    if (t < AA) scid[t] = (int)ann[(b * AA + t) * 5 + 4];
    __syncthreads();

    int p = blockIdx.x * blockDim.x + t;
    float my_r = 0.0f;
    int   my_n = 0;
    if (p < PP) {
        int x = xg[p], y = yg[p], li = lev[p];
        unsigned int em = 0, im = 0;
        for (int a = 0; a < AA; ++a) {
            const int* o = &sb[(a * NLEV + li) * 8];
            int me = (x >= o[0]) & (x <= o[1]) & (y >= o[2]) & (y <= o[3]);
            int mi = (x >= o[4]) & (x <= o[5]) & (y >= o[6]) & (y <= o[7]);
            em |= (unsigned int)me << a;
            im |= (unsigned int)mi << a;
        }
        masks[b * PP + p] = em | (im << 16);

        // distinct positive classes at this position
        unsigned long long lo = 0; unsigned int hi = 0;
        unsigned int m = em;
        while (m) {
            int a = __ffs(m) - 1; m &= m - 1;
            int c = scid[a];
            if (c < 64) lo |= 1ull << c; else hi |= 1u << (c - 64);
        }
        int npos = __popcll(lo) + __popc(hi);

        // box of LAST covering annotation (default A-1 when none)
        int last = em ? (31 - __clz(em)) : (AA - 1);
        const float* pb = &sp[(last * NLEV + li) * 4];
        float xf = (float)x, yf = (float)y;
        float t0 = (xf - pb[0]) * 0.25f;
        float t1 = (pb[2] - xf) * 0.25f;
        float t2 = (yf - pb[1]) * 0.25f;
        float t3 = (pb[3] - yf) * 0.25f;
        const float4 r4 = ((const float4*)reg)[(size_t)b * PP + p];
        float x_gt = (t2 + t3 + 1.0f) * (t0 + t1 + 1.0f);
        float x_pr = (r4.z + r4.w + 1.0f) * (r4.x + r4.y + 1.0f);
        float ih = fminf(t2, r4.z) + fminf(t3, r4.w) + 1.0f;
        float iw = fminf(t0, r4.x) + fminf(t1, r4.y) + 1.0f;
        float inter = ih * iw;
        float iou = inter / (x_pr + x_gt - inter);
        iou = fminf(fmaxf(iou, 1e-4f), 1.0f - 1e-4f);
        float rl = -logf(iou);
        my_r = rl * (float)npos;
        my_n = npos;
    }

    // wave64 + cross-wave reduce, one atomic pair per block
    for (int off = 32; off > 0; off >>= 1) {
        my_r += __shfl_down(my_r, off);
        my_n += __shfl_down(my_n, off);
    }
    int lane = t & 63, wv = t >> 6;
    if (lane == 0) { swr[wv] = my_r; swn[wv] = my_n; }
    __syncthreads();
    if (t == 0) {
        float rs = 0.0f; int ns = 0;
        for (int w = 0; w < (256 >> 6); ++w) { rs += swr[w]; ns += swn[w]; }
        atomicAdd(&reg_sum[b], rs);
        atomicAdd(&n_eff[b], ns);
    }
}

// -------------------------------------------------------------------
// Kernel 3: streaming focal-loss over (b, p, k). Each thread owns
// exactly 8 elements (compile-time unroll) -> 8 independent 16B loads
// in flight per thread for latency hiding; clamped index + predicated
// accumulate handles the tail without conditional loads.
// -------------------------------------------------------------------
__device__ __forceinline__ float focal_term(float c, unsigned int em,
                                            unsigned int im, unsigned int cm)
{
    float cc  = fminf(fmaxf(c, 1e-4f), 1.0f - 1e-4f);
    bool  pos = (em & cm) != 0;
    bool  ign = (!pos) && ((im & cm) != 0);
    float arg = pos ? cc : (1.0f - cc);   // log argument
    float fwt = 1.0f - arg;               // == (pos ? 1-cc : cc)
    float af  = pos ? 0.25f : 0.75f;
    float l   = af * fwt * fwt * (-__logf(arg));
    return ign ? 0.0f : l;
}

#define CLS_U 8
#define CLS_BLOCKS_X 214   // ceil(436480 / (256*8))

__global__ void __launch_bounds__(256, 4)
cls_kernel(const float4* __restrict__ cls4,       // B * (P*K/4)
           const unsigned int* __restrict__ masks,
           const unsigned int* __restrict__ clsmask_g,
           float* __restrict__ cls_sum)
{
    constexpr int V = PP * KK / 4;   // 436480 float4 per image
    __shared__ uint4 scm[KK / 4];    // per-class annotation masks
    __shared__ float sws[4];
    int b = blockIdx.y;
    int t = threadIdx.x;
    if (t < KK / 4) scm[t] = ((const uint4*)clsmask_g)[b * (KK / 4) + t];
    __syncthreads();

    const float4* base = cls4 + (size_t)b * V;
    const unsigned int* mb = masks + b * PP;
    const int stride = CLS_BLOCKS_X * 256;          // 54784
    const int i0 = blockIdx.x * 256 + t;

    float4 c[CLS_U];
    unsigned int mk[CLS_U];
    unsigned int kk[CLS_U];
#pragma unroll
    for (int u = 0; u < CLS_U; ++u) {
        int i  = i0 + u * stride;
        int ic = min(i, V - 1);
        unsigned int p  = (unsigned int)ic / 20u;
        kk[u] = (unsigned int)ic - p * 20u;
        c[u]  = base[ic];
        mk[u] = mb[p];
    }

    float acc = 0.0f;
#pragma unroll
    for (int u = 0; u < CLS_U; ++u) {
        int i = i0 + u * stride;
        unsigned int em = mk[u] & 0xFFFFu, im = mk[u] >> 16;
        uint4 cm = scm[kk[u]];
        float s = focal_term(c[u].x, em, im, cm.x)
                + focal_term(c[u].y, em, im, cm.y)
                + focal_term(c[u].z, em, im, cm.z)
                + focal_term(c[u].w, em, im, cm.w);
        acc += (i < V) ? s : 0.0f;
    }

    for (int off = 32; off > 0; off >>= 1) acc += __shfl_down(acc, off);
    int lane = t & 63, wv = t >> 6;
    if (lane == 0) sws[wv] = acc;
    __syncthreads();
    if (t == 0) {
        atomicAdd(&cls_sum[b], sws[0] + sws[1] + sws[2] + sws[3]);
    }
}

// -------------------------------------------------------------------
// Kernel 4: finalize means
// -------------------------------------------------------------------
__global__ void final_kernel(const float* __restrict__ cls_sum,
                             const float* __restrict__ reg_sum,
                             const int* __restrict__ n_eff,
                             float* __restrict__ out)
{
    int t = threadIdx.x;  // 64 threads, lanes 0..15 active
    float c = 0.0f, r = 0.0f;
    if (t < BB) {
        int n = n_eff[t];
        float d = fmaxf((float)n, 1.0f);
        c = cls_sum[t] / d;
        r = (n > 0) ? (reg_sum[t] / d) : 0.0f;
    }
    for (int off = 32; off > 0; off >>= 1) {
        c += __shfl_down(c, off);
        r += __shfl_down(r, off);
    }
    if (t == 0) {
        out[0] = c * (1.0f / BB);
        out[1] = r * (1.0f / BB);
    }
}

extern "C" void kernel_launch(void* const* d_in, const int* in_sizes, int n_in,
                              void* d_out, int out_size, void* d_ws, size_t ws_size,
                              hipStream_t stream)
{
    const float* cls = (const float*)d_in[0];
    const float* reg = (const float*)d_in[1];
    const float* ann = (const float*)d_in[2];
    // d_in[3] = image (unused)
    const int* xg = (const int*)d_in[4];
    const int* yg = (const int*)d_in[5];
    const int* lv = (const int*)d_in[6];
    float* out = (float*)d_out;

    char* ws = (char*)d_ws;
    float* cls_sum = (float*)(ws + 0);
    float* reg_sum = (float*)(ws + 64);
    int*   n_eff   = (int*)(ws + 128);
    unsigned int* clsmask = (unsigned int*)(ws + WS_CLSMASK);
    int*   bounds  = (int*)(ws + WS_BOUNDS);
    float* proj    = (float*)(ws + WS_PROJ);
    unsigned int* masks = (unsigned int*)(ws + WS_MASKS);

    // zero the accumulators (ws is poisoned 0xAA before every launch)
    hipMemsetAsync(ws, 0, 192, stream);

    prep_kernel<<<10, 256, 0, stream>>>(ann, clsmask, bounds, proj);

    dim3 g2((PP + 255) / 256, BB);
    mask_kernel<<<g2, 256, 0, stream>>>(reg, xg, yg, lv, ann, bounds, proj,
                                        masks, reg_sum, n_eff);

    dim3 g3(CLS_BLOCKS_X, BB);
    cls_kernel<<<g3, 256, 0, stream>>>((const float4*)cls, masks, clsmask, cls_sum);

    final_kernel<<<1, 64, 0, stream>>>(cls_sum, reg_sum, n_eff, out);
}

// Round 3
// 324.939 us; speedup vs baseline: 1.2343x; 1.0730x over previous
//
#include <hip/hip_runtime.h>
#include <cstdint>

// Problem constants (fixed by the reference setup)
#define BB   16      // batch
#define AA   16      // annotations per image
#define KK   80      // classes
#define NLEV 5       // pyramid levels (strides 8..128)
#define PP   21824   // total pyramid positions

#define POS_PER_BLK 256
#define NBLK_X ((PP + POS_PER_BLK - 1) / POS_PER_BLK)   // 86

// ---------------- workspace layout (bytes) ----------------
//   0: float cls_sum[16] | 64: float reg_sum[16] | 128: int n_eff[16]

// Projected-box bounds, identical arithmetic to the reference
// (floor((x+s-1)/s), shrink by 0.4/0.25). fp contract off to stay
// bit-compatible with the validated R0/R1 math.
__device__ __forceinline__ void compute_bounds(const float* __restrict__ bx,
                                               float s, int* __restrict__ o,
                                               float* __restrict__ q)
{
#pragma clang fp contract(off)
    float p0 = floorf((bx[0] + s - 1.0f) / s);
    float p1 = floorf((bx[1] + s - 1.0f) / s);
    float p2 = floorf((bx[2] + s - 1.0f) / s);
    float p3 = floorf((bx[3] + s - 1.0f) / s);
    float pw = p2 - p0, ph = p3 - p1;
    float e0 = p0 + 0.4f * pw,  e1 = p1 + 0.4f * ph;
    float e2 = p2 - 0.4f * pw,  e3 = p3 - 0.4f * ph;
    float i0 = p0 + 0.25f * pw, i1 = p1 + 0.25f * ph;
    float i2 = p2 - 0.25f * pw, i3 = p3 - 0.25f * ph;
    o[0] = (int)floorf(e0);          // eff x >=
    o[1] = (int)floorf(e2 + 1.0f);   // eff x <=
    o[2] = (int)floorf(e1);          // eff y >=
    o[3] = (int)floorf(e3 + 1.0f);   // eff y <=
    o[4] = (int)floorf(i0 + 1.0f);   // ign x >=
    o[5] = (int)floorf(i2);          // ign x <=
    o[6] = (int)floorf(i1 + 1.0f);   // ign y >=
    o[7] = (int)floorf(i3);          // ign y <=
    q[0] = p0; q[1] = p1; q[2] = p2; q[3] = p3;
}

__device__ __forceinline__ float focal_term(float c, unsigned int em,
                                            unsigned int im, unsigned int cm)
{
    float cc  = fminf(fmaxf(c, 1e-4f), 1.0f - 1e-4f);
    bool  pos = (em & cm) != 0;
    bool  ign = (!pos) && ((im & cm) != 0);
    float arg = pos ? cc : (1.0f - cc);   // log argument
    float fwt = 1.0f - arg;               // == (pos ? 1-cc : cc)
    float af  = pos ? 0.25f : 0.75f;
    float l   = af * fwt * fwt * (-__logf(arg));
    return ign ? 0.0f : l;
}

// -------------------------------------------------------------------
// ONE fused kernel. Each block owns 256 consecutive positions of one
// image:
//   phase 0: recompute bounds/proj/clsmask into LDS (tiny, redundant
//            per block but removes 2 kernel launches + global traffic)
//   phase 1: per-position 16-bit eff/ign masks -> LDS; IoU reg loss
//   phase 2: stream the block's 5120 float4 of classifications, 10
//            independent 16B loads in flight per thread
//   epilogue: block-reduce cls/reg/n_eff, one atomic triple per block
// -------------------------------------------------------------------
__global__ void __launch_bounds__(256)
fused_kernel(const float4* __restrict__ cls4,     // B * (P*K/4)
             const float* __restrict__ reg,       // B*P*4
             const float* __restrict__ ann,       // B*A*5
             const int* __restrict__ xg, const int* __restrict__ yg,
             const int* __restrict__ lev,
             float* __restrict__ cls_sum, float* __restrict__ reg_sum,
             int* __restrict__ n_eff)
{
    __shared__ int   sb[AA * NLEV * 8];
    __shared__ float sp[AA * NLEV * 4];
    __shared__ int   scid[AA];
    __shared__ uint4 scm[KK / 4];             // per-class annotation masks
    __shared__ unsigned int smask[POS_PER_BLK];
    __shared__ float swc[4], swr[4];
    __shared__ int   swn[4];

    const int b  = blockIdx.y;
    const int t  = threadIdx.x;
    const int p0 = blockIdx.x * POS_PER_BLK;
    const int npos = min(POS_PER_BLK, PP - p0);

    // ---- phase 0: local prep ----
    const float* annb = ann + b * AA * 5;
    if (t < AA) scid[t] = (int)annb[t * 5 + 4];
    __syncthreads();
    if (t < AA * NLEV) {
        int li = t % NLEV, a = t / NLEV;
        compute_bounds(annb + a * 5, (float)(8 << li), &sb[t * 8], &sp[t * 4]);
    }
    if (t < KK) {
        unsigned int m = 0;
        for (int a = 0; a < AA; ++a)
            if (scid[a] == t) m |= (1u << a);
        ((unsigned int*)scm)[t] = m;
    }
    __syncthreads();

    // ---- phase 1: masks + reg loss (one position per thread) ----
    float my_r = 0.0f; int my_n = 0;
    if (t < npos) {
        int p = p0 + t;
        int x = xg[p], y = yg[p], li = lev[p];
        unsigned int em = 0, im = 0;
        for (int a = 0; a < AA; ++a) {
            const int* o = &sb[(a * NLEV + li) * 8];
            int me = (x >= o[0]) & (x <= o[1]) & (y >= o[2]) & (y <= o[3]);
            int mi = (x >= o[4]) & (x <= o[5]) & (y >= o[6]) & (y <= o[7]);
            em |= (unsigned int)me << a;
            im |= (unsigned int)mi << a;
        }
        smask[t] = em | (im << 16);

        // distinct positive classes at this position
        unsigned long long lo = 0; unsigned int hi = 0;
        unsigned int m = em;
        while (m) {
            int a = __ffs(m) - 1; m &= m - 1;
            int c = scid[a];
            if (c < 64) lo |= 1ull << c; else hi |= 1u << (c - 64);
        }
        int np = __popcll(lo) + __popc(hi);

        // box of LAST covering annotation (default A-1 when none)
        int last = em ? (31 - __clz(em)) : (AA - 1);
        const float* pb = &sp[(last * NLEV + li) * 4];
        float xf = (float)x, yf = (float)y;
        float t0 = (xf - pb[0]) * 0.25f;
        float t1 = (pb[2] - xf) * 0.25f;
        float t2 = (yf - pb[1]) * 0.25f;
        float t3 = (pb[3] - yf) * 0.25f;
        const float4 r4 = ((const float4*)reg)[(size_t)b * PP + p];
        float x_gt = (t2 + t3 + 1.0f) * (t0 + t1 + 1.0f);
        float x_pr = (r4.z + r4.w + 1.0f) * (r4.x + r4.y + 1.0f);
        float ih = fminf(t2, r4.z) + fminf(t3, r4.w) + 1.0f;
        float iw = fminf(t0, r4.x) + fminf(t1, r4.y) + 1.0f;
        float inter = ih * iw;
        float iou = inter / (x_pr + x_gt - inter);
        iou = fminf(fmaxf(iou, 1e-4f), 1.0f - 1e-4f);
        my_r = -logf(iou) * (float)np;
        my_n = np;
    } else {
        smask[t] = 0;   // clamped phase-2 loads may index these; discarded
    }
    __syncthreads();

    // ---- phase 2: stream classifications for this block's positions ----
    const int V  = PP * KK / 4;
    const int nq = npos * (KK / 4);               // float4s in this block
    const float4* cbase = cls4 + (size_t)b * V + (size_t)p0 * (KK / 4);
    float acc = 0.0f;
#pragma unroll
    for (int h = 0; h < 2; ++h) {
        float4 c[10];
        int    idx[10];
#pragma unroll
        for (int u = 0; u < 10; ++u) {
            int il = t + 256 * (h * 10 + u);
            int ic = min(il, nq - 1);
            idx[u] = ic;
            c[u]   = cbase[ic];
        }
#pragma unroll
        for (int u = 0; u < 10; ++u) {
            int il = t + 256 * (h * 10 + u);
            int ic = idx[u];
            unsigned int pl = (unsigned int)ic / 20u;
            unsigned int k4 = (unsigned int)ic - pl * 20u;
            unsigned int mk = smask[pl];
            unsigned int em = mk & 0xFFFFu, im = mk >> 16;
            uint4 cm = scm[k4];
            float s = focal_term(c[u].x, em, im, cm.x)
                    + focal_term(c[u].y, em, im, cm.y)
                    + focal_term(c[u].z, em, im, cm.z)
                    + focal_term(c[u].w, em, im, cm.w);
            acc += (il < nq) ? s : 0.0f;
        }
    }

    // ---- epilogue: block reduce, one atomic triple per block ----
    for (int off = 32; off > 0; off >>= 1) {
        acc  += __shfl_down(acc,  off);
        my_r += __shfl_down(my_r, off);
        my_n += __shfl_down(my_n, off);
    }
    int lane = t & 63, wv = t >> 6;
    if (lane == 0) { swc[wv] = acc; swr[wv] = my_r; swn[wv] = my_n; }
    __syncthreads();
    if (t == 0) {
        float cs = swc[0] + swc[1] + swc[2] + swc[3];
        float rs = swr[0] + swr[1] + swr[2] + swr[3];
        int   ns = swn[0] + swn[1] + swn[2] + swn[3];
        atomicAdd(&cls_sum[b], cs);
        atomicAdd(&reg_sum[b], rs);
        atomicAdd(&n_eff[b], ns);
    }
}

// -------------------------------------------------------------------
// finalize means
// -------------------------------------------------------------------
__global__ void final_kernel(const float* __restrict__ cls_sum,
                             const float* __restrict__ reg_sum,
                             const int* __restrict__ n_eff,
                             float* __restrict__ out)
{
    int t = threadIdx.x;  // 64 threads, lanes 0..15 active
    float c = 0.0f, r = 0.0f;
    if (t < BB) {
        int n = n_eff[t];
        float d = fmaxf((float)n, 1.0f);
        c = cls_sum[t] / d;
        r = (n > 0) ? (reg_sum[t] / d) : 0.0f;
    }
    for (int off = 32; off > 0; off >>= 1) {
        c += __shfl_down(c, off);
        r += __shfl_down(r, off);
    }
    if (t == 0) {
        out[0] = c * (1.0f / BB);
        out[1] = r * (1.0f / BB);
    }
}

extern "C" void kernel_launch(void* const* d_in, const int* in_sizes, int n_in,
                              void* d_out, int out_size, void* d_ws, size_t ws_size,
                              hipStream_t stream)
{
    const float* cls = (const float*)d_in[0];
    const float* reg = (const float*)d_in[1];
    const float* ann = (const float*)d_in[2];
    // d_in[3] = image (unused)
    const int* xg = (const int*)d_in[4];
    const int* yg = (const int*)d_in[5];
    const int* lv = (const int*)d_in[6];
    float* out = (float*)d_out;

    char* ws = (char*)d_ws;
    float* cls_sum = (float*)(ws + 0);
    float* reg_sum = (float*)(ws + 64);
    int*   n_eff   = (int*)(ws + 128);

    // zero the accumulators (ws is poisoned 0xAA before every launch)
    hipMemsetAsync(ws, 0, 192, stream);

    dim3 grid(NBLK_X, BB);
    fused_kernel<<<grid, 256, 0, stream>>>((const float4*)cls, reg, ann,
                                           xg, yg, lv,
                                           cls_sum, reg_sum, n_eff);

    final_kernel<<<1, 64, 0, stream>>>(cls_sum, reg_sum, n_eff, out);
}

// Round 4
// 321.695 us; speedup vs baseline: 1.2468x; 1.0101x over previous
//
#include <hip/hip_runtime.h>
#include <cstdint>

// Problem constants (fixed by the reference setup)
#define BB   16      // batch
#define AA   16      // annotations per image
#define KK   80      // classes
#define NLEV 5       // pyramid levels (strides 8..128)
#define PP   21824   // total pyramid positions

#define POS_PER_BLK 256
#define NBLK_X ((PP + POS_PER_BLK - 1) / POS_PER_BLK)   // 86; blocks 0..84 full, block 85 has 64 pos

// ---------------- workspace layout (bytes) ----------------
//   0: float cls_sum[16] | 64: float reg_sum[16] | 128: int n_eff[16]

// Projected-box bounds, identical arithmetic to the reference.
__device__ __forceinline__ void compute_bounds(const float* __restrict__ bx,
                                               float s, int* __restrict__ o,
                                               float* __restrict__ q)
{
#pragma clang fp contract(off)
    float p0 = floorf((bx[0] + s - 1.0f) / s);
    float p1 = floorf((bx[1] + s - 1.0f) / s);
    float p2 = floorf((bx[2] + s - 1.0f) / s);
    float p3 = floorf((bx[3] + s - 1.0f) / s);
    float pw = p2 - p0, ph = p3 - p1;
    float e0 = p0 + 0.4f * pw,  e1 = p1 + 0.4f * ph;
    float e2 = p2 - 0.4f * pw,  e3 = p3 - 0.4f * ph;
    float i0 = p0 + 0.25f * pw, i1 = p1 + 0.25f * ph;
    float i2 = p2 - 0.25f * pw, i3 = p3 - 0.25f * ph;
    o[0] = (int)floorf(e0);          // eff x >=
    o[1] = (int)floorf(e2 + 1.0f);   // eff x <=
    o[2] = (int)floorf(e1);          // eff y >=
    o[3] = (int)floorf(e3 + 1.0f);   // eff y <=
    o[4] = (int)floorf(i0 + 1.0f);   // ign x >=
    o[5] = (int)floorf(i2);          // ign x <=
    o[6] = (int)floorf(i1 + 1.0f);   // ign y >=
    o[7] = (int)floorf(i3);          // ign y <=
    q[0] = p0; q[1] = p1; q[2] = p2; q[3] = p3;
}

__device__ __forceinline__ float focal_term(float c, unsigned int em,
                                            unsigned int im, unsigned int cm)
{
    float cc  = fminf(fmaxf(c, 1e-4f), 1.0f - 1e-4f);
    bool  pos = (em & cm) != 0;
    bool  ign = (!pos) && ((im & cm) != 0);
    float arg = pos ? cc : (1.0f - cc);   // log argument
    float fwt = 1.0f - arg;               // == (pos ? 1-cc : cc)
    float af  = pos ? 0.25f : 0.75f;
    float l   = af * fwt * fwt * (-__logf(arg));
    return ign ? 0.0f : l;
}

// -------------------------------------------------------------------
// ONE fused kernel; each block owns 256 consecutive positions of one
// image. PP = 85*256 + 64, so full blocks process exactly 20 float4
// per thread and the tail block exactly 5 -- no predication anywhere.
// Batch 0 of the cls loads is issued BEFORE the mask phase so the
// streaming traffic flies under phase-0/1 compute and the barrier.
// -------------------------------------------------------------------
__global__ void __launch_bounds__(256)
fused_kernel(const float4* __restrict__ cls4,     // B * (P*K/4)
             const float* __restrict__ reg,       // B*P*4
             const float* __restrict__ ann,       // B*A*5
             const int* __restrict__ xg, const int* __restrict__ yg,
             const int* __restrict__ lev,
             float* __restrict__ cls_sum, float* __restrict__ reg_sum,
             int* __restrict__ n_eff)
{
    __shared__ int   sb[AA * NLEV * 8];
    __shared__ float sp[AA * NLEV * 4];
    __shared__ int   scid[AA];
    __shared__ uint4 scm[KK / 4];             // per-class annotation masks
    __shared__ unsigned int smask[POS_PER_BLK];
    __shared__ float swc[4], swr[4];
    __shared__ int   swn[4];

    const int  b    = blockIdx.y;
    const int  t    = threadIdx.x;
    const int  p0   = blockIdx.x * POS_PER_BLK;
    const bool full = (blockIdx.x < NBLK_X - 1);
    const int  npos = full ? POS_PER_BLK : (PP - (NBLK_X - 1) * POS_PER_BLK); // 256 or 64

    const int V = PP * KK / 4;
    const float4* cbase = cls4 + (size_t)b * V + (size_t)p0 * (KK / 4);

    // ---- prefetch batch 0 of the streaming cls loads (10 or 5 float4) ----
    float4 c0[10];
    if (full) {
#pragma unroll
        for (int u = 0; u < 10; ++u) c0[u] = cbase[t + 256 * u];
    } else {
#pragma unroll
        for (int u = 0; u < 5; ++u)  c0[u] = cbase[t + 256 * u];
    }

    // ---- phase 0: local prep (runs while batch 0 is in flight) ----
    const float* annb = ann + b * AA * 5;
    if (t < AA) scid[t] = (int)annb[t * 5 + 4];
    __syncthreads();
    if (t < AA * NLEV) {
        int li = t % NLEV, a = t / NLEV;
        compute_bounds(annb + a * 5, (float)(8 << li), &sb[t * 8], &sp[t * 4]);
    }
    if (t < KK) {
        unsigned int m = 0;
        for (int a = 0; a < AA; ++a)
            if (scid[a] == t) m |= (1u << a);
        ((unsigned int*)scm)[t] = m;
    }
    __syncthreads();

    // ---- phase 1: masks + reg loss (one position per thread) ----
    float my_r = 0.0f; int my_n = 0;
    if (t < npos) {
        int p = p0 + t;
        int x = xg[p], y = yg[p], li = lev[p];
        unsigned int em = 0, im = 0;
        for (int a = 0; a < AA; ++a) {
            const int* o = &sb[(a * NLEV + li) * 8];
            int me = (x >= o[0]) & (x <= o[1]) & (y >= o[2]) & (y <= o[3]);
            int mi = (x >= o[4]) & (x <= o[5]) & (y >= o[6]) & (y <= o[7]);
            em |= (unsigned int)me << a;
            im |= (unsigned int)mi << a;
        }
        smask[t] = em | (im << 16);

        // distinct positive classes at this position
        unsigned long long lo = 0; unsigned int hi = 0;
        unsigned int m = em;
        while (m) {
            int a = __ffs(m) - 1; m &= m - 1;
            int c = scid[a];
            if (c < 64) lo |= 1ull << c; else hi |= 1u << (c - 64);
        }
        int np = __popcll(lo) + __popc(hi);

        // box of LAST covering annotation (default A-1 when none)
        int last = em ? (31 - __clz(em)) : (AA - 1);
        const float* pb = &sp[(last * NLEV + li) * 4];
        float xf = (float)x, yf = (float)y;
        float t0 = (xf - pb[0]) * 0.25f;
        float t1 = (pb[2] - xf) * 0.25f;
        float t2 = (yf - pb[1]) * 0.25f;
        float t3 = (pb[3] - yf) * 0.25f;
        const float4 r4 = ((const float4*)reg)[(size_t)b * PP + p];
        float x_gt = (t2 + t3 + 1.0f) * (t0 + t1 + 1.0f);
        float x_pr = (r4.z + r4.w + 1.0f) * (r4.x + r4.y + 1.0f);
        float ih = fminf(t2, r4.z) + fminf(t3, r4.w) + 1.0f;
        float iw = fminf(t0, r4.x) + fminf(t1, r4.y) + 1.0f;
        float inter = ih * iw;
        float iou = inter / (x_pr + x_gt - inter);
        iou = fminf(fmaxf(iou, 1e-4f), 1.0f - 1e-4f);
        my_r = -logf(iou) * (float)np;
        my_n = np;
    }
    __syncthreads();

    // ---- phase 2: consume batch 0, overlap batch 1 loads (full blocks) ----
    float acc = 0.0f;
    if (full) {
        float4 c1[10];
#pragma unroll
        for (int u = 0; u < 10; ++u) c1[u] = cbase[t + 256 * (10 + u)];   // issue batch 1
#pragma unroll
        for (int u = 0; u < 10; ++u) {                                    // consume batch 0
            unsigned int il = (unsigned int)(t + 256 * u);
            unsigned int pl = il / 20u, k4 = il - pl * 20u;
            unsigned int mk = smask[pl];
            unsigned int em = mk & 0xFFFFu, im = mk >> 16;
            uint4 cm = scm[k4];
            acc += focal_term(c0[u].x, em, im, cm.x)
                 + focal_term(c0[u].y, em, im, cm.y)
                 + focal_term(c0[u].z, em, im, cm.z)
                 + focal_term(c0[u].w, em, im, cm.w);
        }
#pragma unroll
        for (int u = 0; u < 10; ++u) {                                    // consume batch 1
            unsigned int il = (unsigned int)(t + 256 * (10 + u));
            unsigned int pl = il / 20u, k4 = il - pl * 20u;
            unsigned int mk = smask[pl];
            unsigned int em = mk & 0xFFFFu, im = mk >> 16;
            uint4 cm = scm[k4];
            acc += focal_term(c1[u].x, em, im, cm.x)
                 + focal_term(c1[u].y, em, im, cm.y)
                 + focal_term(c1[u].z, em, im, cm.z)
                 + focal_term(c1[u].w, em, im, cm.w);
        }
    } else {
#pragma unroll
        for (int u = 0; u < 5; ++u) {
            unsigned int il = (unsigned int)(t + 256 * u);
            unsigned int pl = il / 20u, k4 = il - pl * 20u;
            unsigned int mk = smask[pl];
            unsigned int em = mk & 0xFFFFu, im = mk >> 16;
            uint4 cm = scm[k4];
            acc += focal_term(c0[u].x, em, im, cm.x)
                 + focal_term(c0[u].y, em, im, cm.y)
                 + focal_term(c0[u].z, em, im, cm.z)
                 + focal_term(c0[u].w, em, im, cm.w);
        }
    }

    // ---- epilogue: block reduce, one atomic triple per block ----
    for (int off = 32; off > 0; off >>= 1) {
        acc  += __shfl_down(acc,  off);
        my_r += __shfl_down(my_r, off);
        my_n += __shfl_down(my_n, off);
    }
    int lane = t & 63, wv = t >> 6;
    if (lane == 0) { swc[wv] = acc; swr[wv] = my_r; swn[wv] = my_n; }
    __syncthreads();
    if (t == 0) {
        atomicAdd(&cls_sum[b], swc[0] + swc[1] + swc[2] + swc[3]);
        atomicAdd(&reg_sum[b], swr[0] + swr[1] + swr[2] + swr[3]);
        atomicAdd(&n_eff[b],   swn[0] + swn[1] + swn[2] + swn[3]);
    }
}

// -------------------------------------------------------------------
// finalize means
// -------------------------------------------------------------------
__global__ void final_kernel(const float* __restrict__ cls_sum,
                             const float* __restrict__ reg_sum,
                             const int* __restrict__ n_eff,
                             float* __restrict__ out)
{
    int t = threadIdx.x;  // 64 threads, lanes 0..15 active
    float c = 0.0f, r = 0.0f;
    if (t < BB) {
        int n = n_eff[t];
        float d = fmaxf((float)n, 1.0f);
        c = cls_sum[t] / d;
        r = (n > 0) ? (reg_sum[t] / d) : 0.0f;
    }
    for (int off = 32; off > 0; off >>= 1) {
        c += __shfl_down(c, off);
        r += __shfl_down(r, off);
    }
    if (t == 0) {
        out[0] = c * (1.0f / BB);
        out[1] = r * (1.0f / BB);
    }
}

extern "C" void kernel_launch(void* const* d_in, const int* in_sizes, int n_in,
                              void* d_out, int out_size, void* d_ws, size_t ws_size,
                              hipStream_t stream)
{
    const float* cls = (const float*)d_in[0];
    const float* reg = (const float*)d_in[1];
    const float* ann = (const float*)d_in[2];
    // d_in[3] = image (unused)
    const int* xg = (const int*)d_in[4];
    const int* yg = (const int*)d_in[5];
    const int* lv = (const int*)d_in[6];
    float* out = (float*)d_out;

    char* ws = (char*)d_ws;
    float* cls_sum = (float*)(ws + 0);
    float* reg_sum = (float*)(ws + 64);
    int*   n_eff   = (int*)(ws + 128);

    // zero the accumulators (ws is poisoned 0xAA before every launch)
    hipMemsetAsync(ws, 0, 192, stream);

    dim3 grid(NBLK_X, BB);
    fused_kernel<<<grid, 256, 0, stream>>>((const float4*)cls, reg, ann,
                                           xg, yg, lv,
                                           cls_sum, reg_sum, n_eff);

    final_kernel<<<1, 64, 0, stream>>>(cls_sum, reg_sum, n_eff, out);
}